// Round 2
// baseline (196.371 us; speedup 1.0000x reference)
//
#include <hip/hip_runtime.h>

typedef _Float16 f16;
typedef _Float16 f16x2 __attribute__((ext_vector_type(2)));
typedef _Float16 f16x8 __attribute__((ext_vector_type(8)));
typedef float    f32x4 __attribute__((ext_vector_type(4)));

#define DIM 128

// silu(x) = x / (1 + e^-x); v_exp_f32 is 2^x so scale by log2(e). v_rcp_f32 ~1ulp.
__device__ __forceinline__ float silu_f(float x) {
    float e = __builtin_amdgcn_exp2f(x * -1.44269504088896341f);
    return x * __builtin_amdgcn_rcpf(1.0f + e);
}

// Barrier-free M-split, occupancy-maximized: block = 1024 threads = 16 waves,
// ONE block per CU. Each wave owns 16 rows per tile end-to-end (block-tile = 256
// rows); weights live in LDS f16 B-frags shared by all 16 waves (64 KB, amortized),
// x1 staging is WAVE-PRIVATE (4 KB/wave, XOR-swizzled) so the main loop has ZERO
// __syncthreads -> no forced vmcnt(0) store drains, 16 independent wave pipelines.
// LDS total 128 KB -> 1 block/CU = 16 waves/CU (4/SIMD).
__global__ __launch_bounds__(1024, 4)
void ts_mlp_kernel(const float* __restrict__ t,
                   const float* __restrict__ W1, const float* __restrict__ b1,
                   const float* __restrict__ W2, const float* __restrict__ b2,
                   float* __restrict__ out, int B) {
    // B-frag layout: frag for (kt, nt) in lane L holds W[n][k] with
    //   n = nt*16 + (L&15), k = kt*32 + (L>>4)*8 + j, j=0..7
    __shared__ f16x8 w1f[4][8][64];     // 32 KB
    __shared__ f16x8 w2f[4][8][64];     // 32 KB
    // x1 staging per wave: 16 rows x 128 k as 16B chunks; chunk (m, c=k>>3) at
    // physical m*16 + (c ^ m) -> <=2-way banked reads and writes.
    __shared__ f16x2 x1p[16][256][4];   // 64 KB

    const int tid  = threadIdx.x;
    const int wv   = tid >> 6;
    const int lane = tid & 63;
    const int q    = lane >> 4;   // quad index 0..3
    const int ln   = lane & 15;
    const int par  = lane & 1;

    // ---- prologue: 16 waves stage 16 (matrix, nt) pairs -> LDS fp16 fragments
    {
        const int mtx = wv >> 3;          // waves 0-7: W1, waves 8-15: W2
        const int nt  = wv & 7;
        const float* W = mtx ? W2 : W1;
        const int n = nt * 16 + ln;
#pragma unroll
        for (int kt = 0; kt < 4; ++kt) {
            const int k0 = kt * 32 + q * 8;
            const float4* src = (const float4*)(W + n * DIM + k0);
            float4 lo = src[0], hi = src[1];
            f16x8 fr;
            fr[0] = (f16)lo.x; fr[1] = (f16)lo.y; fr[2] = (f16)lo.z; fr[3] = (f16)lo.w;
            fr[4] = (f16)hi.x; fr[5] = (f16)hi.y; fr[6] = (f16)hi.z; fr[7] = (f16)hi.w;
            if (mtx) w2f[kt][nt][lane] = fr; else w1f[kt][nt][lane] = fr;
        }
    }
    float b1v[8], b2v[8];
#pragma unroll
    for (int nt = 0; nt < 8; ++nt) {
        b1v[nt] = b1[nt * 16 + ln];
        b2v[nt] = b2[nt * 16 + ln];
    }
    __syncthreads();   // the ONLY barrier in the kernel

    const int ntiles = B >> 8;            // 256 rows per block-tile
    int tile = blockIdx.x;
    // prefetch t one tile ahead (hides HBM-miss latency at tile start)
    float tv_next = (tile < ntiles) ? t[tile * 256 + wv * 16 + ln] : 0.0f;

    for (; tile < ntiles; tile += gridDim.x) {
        const float tv = tv_next;
        const int nxt = tile + gridDim.x;
        if (nxt < ntiles) tv_next = t[nxt * 256 + wv * 16 + ln];
        const int row0 = tile * 256 + wv * 16;

        // ---- emb directly in A-frag layout: row m = ln, k = kt*32 + q*8 + j
        // v_sin/v_cos take REVOLUTIONS: phase_d * t / 2pi = d*t/256
        const float t256 = tv * 0.00390625f;
        const float o256 = (1.0f - tv) * 0.00390625f;
        f16x8 af[4];
#pragma unroll
        for (int kt = 0; kt < 4; ++kt) {
#pragma unroll
            for (int j = 0; j < 8; ++j) {
                const float fd = (float)(kt * 32 + q * 8 + j);
                const float c  = __builtin_amdgcn_cosf(fd * t256);
                const float s  = __builtin_amdgcn_sinf(fd * o256);
                af[kt][j] = (f16)(tv * (c + s));
            }
        }

        // ---- layer 1: 32 MFMAs, B-frags from shared LDS
        f32x4 acc[8];
#pragma unroll
        for (int nt = 0; nt < 8; ++nt) acc[nt] = (f32x4){0.f, 0.f, 0.f, 0.f};
#pragma unroll
        for (int kt = 0; kt < 4; ++kt) {
#pragma unroll
            for (int nt = 0; nt < 8; ++nt) {
                acc[nt] = __builtin_amdgcn_mfma_f32_16x16x32_f16(
                    af[kt], w1f[kt][nt][lane], acc[nt], 0, 0, 0);
            }
        }

        // ---- epilogue 1: bias + silu, pack col-pairs cross-lane, write x1 (fp16)
        // C layout: value r in lane L is x1[row = q*4 + r][col = nt*16 + ln]
#pragma unroll
        for (int nt = 0; nt < 8; ++nt) {
            float v[4], pv[4];
#pragma unroll
            for (int r = 0; r < 4; ++r) v[r] = silu_f(acc[nt][r] + b1v[nt]);
#pragma unroll
            for (int r = 0; r < 4; ++r) pv[r] = __shfl_xor(v[r], 1, 64);
            const int k0  = nt * 16 + (ln & 14);   // even column of the pair
            const int cch = k0 >> 3;               // 16B chunk index
            const int hw  = (k0 & 7) >> 1;         // dword within chunk
#pragma unroll
            for (int p = 0; p < 2; ++p) {
                const int r = par * 2 + p;         // even lanes write rows r=0,1; odd r=2,3
                const int m = q * 4 + r;
                const float lo = par ? pv[r] : v[r];
                const float hi = par ? v[r] : pv[r];
                f16x2 h; h.x = (f16)lo; h.y = (f16)hi;
                x1p[wv][m * 16 + (cch ^ m)][hw] = h;
            }
        }
        // x1p slice is private to this wave; same-wave DS ops are in-order -> no barrier.

        // ---- layer 2: A-frags from swizzled x1, 32 MFMAs
        f32x4 acc2[8];
#pragma unroll
        for (int nt = 0; nt < 8; ++nt) acc2[nt] = (f32x4){0.f, 0.f, 0.f, 0.f};
#pragma unroll
        for (int kt = 0; kt < 4; ++kt) {
            const f16x8 a2 = *(const f16x8*)&x1p[wv][ln * 16 + ((kt * 4 + q) ^ ln)][0];
#pragma unroll
            for (int nt = 0; nt < 8; ++nt) {
                acc2[nt] = __builtin_amdgcn_mfma_f32_16x16x32_f16(
                    a2, w2f[kt][nt][lane], acc2[nt], 0, 0, 0);
            }
        }

        // ---- epilogue 2: bias + silu, fp32 store (64B segments per 16-lane group)
#pragma unroll
        for (int nt = 0; nt < 8; ++nt) {
#pragma unroll
            for (int r = 0; r < 4; ++r) {
                const float o = silu_f(acc2[nt][r] + b2v[nt]);
                out[(size_t)(row0 + q * 4 + r) * DIM + nt * 16 + ln] = o;
            }
        }
    }
}

extern "C" void kernel_launch(void* const* d_in, const int* in_sizes, int n_in,
                              void* d_out, int out_size, void* d_ws, size_t ws_size,
                              hipStream_t stream) {
    const float* t  = (const float*)d_in[0];
    const float* W1 = (const float*)d_in[1];
    const float* b1 = (const float*)d_in[2];
    const float* W2 = (const float*)d_in[3];
    const float* b2 = (const float*)d_in[4];
    float* out = (float*)d_out;
    const int B = in_sizes[0];
    const int ntiles = B >> 8;              // 256 rows per block-tile
    // 1 block/CU (128 KB LDS); 256 blocks x 4 tiles each, perfectly balanced
    int grid = ntiles < 256 ? ntiles : 256;
    ts_mlp_kernel<<<dim3(grid), dim3(1024), 0, stream>>>(t, W1, b1, W2, b2, out, B);
}

// Round 4
// 194.569 us; speedup vs baseline: 1.0093x; 1.0093x over previous
//
#include <hip/hip_runtime.h>

typedef _Float16 f16;
typedef _Float16 f16x2 __attribute__((ext_vector_type(2)));
typedef _Float16 f16x8 __attribute__((ext_vector_type(8)));
typedef float    f32x16 __attribute__((ext_vector_type(16)));

#define DIM 128

// silu(x) = x / (1 + e^-x); v_exp_f32 is 2^x so scale by log2(e). v_rcp_f32 ~1ulp.
__device__ __forceinline__ float silu_f(float x) {
    float e = __builtin_amdgcn_exp2f(x * -1.44269504088896341f);
    return x * __builtin_amdgcn_rcpf(1.0f + e);
}

// Barrier-free M-split on 32x32x16 MFMA: block = 512 threads = 8 waves, each wave
// owns 32 rows end-to-end (block-tile = 256 rows). vs the 16x16x32 version this
// HALVES MFMA instructions and weight ds_read_b128 per row, shortening the per-wave
// serial chain. Weights live in LDS B-frags (64 KB shared); x1 is WAVE-PRIVATE
// (8 KB/wave, XOR-swizzled 16B chunks) -> zero main-loop barriers. LDS = 128 KB ->
// 1 block/CU = 8 waves/CU; __launch_bounds__(512,2) -> 256-VGPR budget so the
// scheduler can pipeline fragment loads.
// r3 fix: layer-2 read swizzle must mask the XOR to the 16-chunk row range:
// (kt*2+h) ^ (l31 & 15)  [unmasked l31 read OOB for l31>=16 -> NaN].
__global__ __launch_bounds__(512, 2)
void ts_mlp_kernel(const float* __restrict__ t,
                   const float* __restrict__ W1, const float* __restrict__ b1,
                   const float* __restrict__ W2, const float* __restrict__ b2,
                   float* __restrict__ out, int B) {
    // B-frag (32x32x16): frag (kt, nt) in lane L holds W[n][k] with
    //   n = nt*32 + (L&31), k = kt*16 + (L>>5)*8 + j, j=0..7
    __shared__ f16x8 w1f[8][4][64];     // 32 KB
    __shared__ f16x8 w2f[8][4][64];     // 32 KB
    // x1 per wave: 32 rows x 128 cols f16 as 16B chunks; chunk (row, c=col>>3) at
    // physical row*16 + (c ^ (row&15)) -> <=2-way banked on both write and read.
    __shared__ f16x2 x1p[8][512][4];    // 64 KB

    const int tid  = threadIdx.x;
    const int wv   = tid >> 6;
    const int lane = tid & 63;
    const int h    = lane >> 5;    // half-wave index (k-group for A/B frags)
    const int l31  = lane & 31;
    const int par  = lane & 1;

    // ---- prologue: wave wv stages k-tile kt=wv of both matrices -> LDS B-frags
    {
        const int kt = wv;
        const int k0 = kt * 16 + h * 8;
#pragma unroll
        for (int mtx = 0; mtx < 2; ++mtx) {
            const float* W = mtx ? W2 : W1;
#pragma unroll
            for (int nt = 0; nt < 4; ++nt) {
                const int n = nt * 32 + l31;
                const float4* src = (const float4*)(W + n * DIM + k0);
                float4 lo = src[0], hi = src[1];
                f16x8 fr;
                fr[0] = (f16)lo.x; fr[1] = (f16)lo.y; fr[2] = (f16)lo.z; fr[3] = (f16)lo.w;
                fr[4] = (f16)hi.x; fr[5] = (f16)hi.y; fr[6] = (f16)hi.z; fr[7] = (f16)hi.w;
                if (mtx) w2f[kt][nt][lane] = fr; else w1f[kt][nt][lane] = fr;
            }
        }
    }
    float b1v[4], b2v[4];
#pragma unroll
    for (int nt = 0; nt < 4; ++nt) {
        b1v[nt] = b1[nt * 32 + l31];
        b2v[nt] = b2[nt * 32 + l31];
    }
    __syncthreads();   // the ONLY barrier in the kernel

    const int ntiles = B >> 8;            // 256 rows per block-tile
    int tile = blockIdx.x;
    float tv_next = (tile < ntiles) ? t[tile * 256 + wv * 32 + l31] : 0.0f;
    const float h8f = (float)(h * 8);

    for (; tile < ntiles; tile += gridDim.x) {
        const float tv = tv_next;
        const int nxt = tile + gridDim.x;
        if (nxt < ntiles) tv_next = t[nxt * 256 + wv * 32 + l31];
        const int row0 = tile * 256 + wv * 32;

        // ---- emb directly in 32x32 A-frag layout: row m = l31, k = kt*16 + h*8 + j
        // v_sin/v_cos take REVOLUTIONS: phase_d * t / 2pi = d*t/256
        const float t256 = tv * 0.00390625f;
        const float o256 = (1.0f - tv) * 0.00390625f;
        f16x8 af[8];
#pragma unroll
        for (int kt = 0; kt < 8; ++kt) {
#pragma unroll
            for (int j = 0; j < 8; ++j) {
                const float fd = (float)(kt * 16 + j) + h8f;
                const float c  = __builtin_amdgcn_cosf(fd * t256);
                const float s  = __builtin_amdgcn_sinf(fd * o256);
                af[kt][j] = (f16)(tv * (c + s));
            }
        }

        // ---- layer 1: 32 MFMAs (32x32x16), B-frags from shared LDS
        f32x16 acc[4];
#pragma unroll
        for (int nt = 0; nt < 4; ++nt)
#pragma unroll
            for (int r = 0; r < 16; ++r) acc[nt][r] = 0.0f;
#pragma unroll
        for (int kt = 0; kt < 8; ++kt) {
#pragma unroll
            for (int nt = 0; nt < 4; ++nt) {
                acc[nt] = __builtin_amdgcn_mfma_f32_32x32x16_f16(
                    af[kt], w1f[kt][nt][lane], acc[nt], 0, 0, 0);
            }
        }

        // ---- epilogue 1: bias + silu, pack col-pairs cross-lane, write x1 (fp16)
        // C layout: reg r in lane L is x1[row = (r&3)+8*(r>>2)+4*h][col = nt*32 + l31]
#pragma unroll
        for (int nt = 0; nt < 4; ++nt) {
            float v[16], pv[16];
#pragma unroll
            for (int r = 0; r < 16; ++r) v[r] = silu_f(acc[nt][r] + b1v[nt]);
#pragma unroll
            for (int r = 0; r < 16; ++r) pv[r] = __shfl_xor(v[r], 1, 64);
            const int cch = nt * 4 + ((lane & 30) >> 3);   // 16B chunk index
            const int dw  = (lane & 6) >> 1;               // dword within chunk
#pragma unroll
            for (int w8 = 0; w8 < 8; ++w8) {
                const int r   = par * 8 + w8;   // even lanes write r=0..7, odd r=8..15
                const int row = (r & 3) + 8 * (r >> 2) + 4 * h;
                const float lo = par ? pv[r] : v[r];
                const float hi = par ? v[r] : pv[r];
                f16x2 hh; hh.x = (f16)lo; hh.y = (f16)hi;
                x1p[wv][row * 16 + (cch ^ (row & 15))][dw] = hh;
            }
        }
        // x1p slice is private to this wave; same-wave DS ops are in-order -> no barrier.

        // ---- layer 2: A-frags from swizzled x1 (8 ds_read_b128), 32 MFMAs
        f32x16 acc2[4];
#pragma unroll
        for (int nt = 0; nt < 4; ++nt)
#pragma unroll
            for (int r = 0; r < 16; ++r) acc2[nt][r] = 0.0f;
#pragma unroll
        for (int kt = 0; kt < 8; ++kt) {
            // row = l31, chunk c = kt*2 + h; physical = l31*16 + (c ^ (l31 & 15))
            const f16x8 a2 = *(const f16x8*)&x1p[wv][l31 * 16 + ((kt * 2 + h) ^ (l31 & 15))][0];
#pragma unroll
            for (int nt = 0; nt < 4; ++nt) {
                acc2[nt] = __builtin_amdgcn_mfma_f32_32x32x16_f16(
                    a2, w2f[kt][nt][lane], acc2[nt], 0, 0, 0);
            }
        }

        // ---- epilogue 2: bias + silu, fp32 store; lanes 0-31 cover one FULL 128B
        // line (cols nt*32..nt*32+31 of one row), lanes 32-63 another -> 2 lines/instr
#pragma unroll
        for (int nt = 0; nt < 4; ++nt) {
#pragma unroll
            for (int r = 0; r < 16; ++r) {
                const int row = (r & 3) + 8 * (r >> 2) + 4 * h;
                const float o = silu_f(acc2[nt][r] + b2v[nt]);
                out[(size_t)(row0 + row) * DIM + nt * 32 + l31] = o;
            }
        }
    }
}

extern "C" void kernel_launch(void* const* d_in, const int* in_sizes, int n_in,
                              void* d_out, int out_size, void* d_ws, size_t ws_size,
                              hipStream_t stream) {
    const float* t  = (const float*)d_in[0];
    const float* W1 = (const float*)d_in[1];
    const float* b1 = (const float*)d_in[2];
    const float* W2 = (const float*)d_in[3];
    const float* b2 = (const float*)d_in[4];
    float* out = (float*)d_out;
    const int B = in_sizes[0];
    const int ntiles = B >> 8;              // 256 rows per block-tile
    // 1 block/CU (128 KB LDS); 256 blocks x 4 tiles each, perfectly balanced
    int grid = ntiles < 256 ? ntiles : 256;
    ts_mlp_kernel<<<dim3(grid), dim3(512), 0, stream>>>(t, W1, b1, W2, b2, out, B);
}